// Round 7
// baseline (415.593 us; speedup 1.0000x reference)
//
#include <hip/hip_runtime.h>

#define NN 100000
#define EE 1600000
#define NCOPY 8
#define FB 782    // edge blocks: (EE/8 + 255)/256
#define GB 1563   // gemm1 blocks: (NN + 63)/64
#define IMASK 0x1FFFF   // low 17 bits: source index (NN=100000 sentinel fits)

typedef short bf16x8 __attribute__((ext_vector_type(8)));
typedef float floatx4 __attribute__((ext_vector_type(4)));

__device__ __forceinline__ unsigned short f2bf(float f) {
    unsigned int u = __float_as_uint(f);
    u = (u + 0x7FFF + ((u >> 16) & 1)) >> 16;   // round-to-nearest-even
    return (unsigned short)u;
}
__device__ __forceinline__ float bf2f_lo(unsigned int packed) {
    return __uint_as_float(packed << 16);
}
__device__ __forceinline__ float bf2f_hi(unsigned int packed) {
    return __uint_as_float(packed & 0xFFFF0000u);
}

// ---------------- MFMA GEMM body ---------------------------------------------
// C[M,F] = A[M,128] @ W[F,128].T. Layouts (learn_hip m89):
// A[m=lane&15][k=quad*8+j], B[n=lane&15][k=quad*8+j], C/D col=lane&15 row=quad*4+reg.
// B_F32: convert W from f32 inline (allows running before any cvt kernel).

template <int F, bool A_F32, bool B_F32, bool OUT_BF16>
__device__ __forceinline__ void gemm_body(int blk, int tid,
                                          const void* __restrict__ A_,
                                          const void* __restrict__ Wb_,
                                          const float* __restrict__ bias,
                                          void* __restrict__ Cout, int M) {
    int wave = tid >> 6, lane = tid & 63;
    int quad = lane >> 4, r16 = lane & 15;
    int node0 = blk * 64 + wave * 16;

    int arow = node0 + r16;
    if (arow >= M) arow = M - 1;                 // clamp read; stores guarded

    bf16x8 af[4];
    if (A_F32) {
        const float* Ap = (const float*)A_ + (size_t)arow * 128 + quad * 8;
#pragma unroll
        for (int ks = 0; ks < 4; ks++) {
            float4 x0 = *(const float4*)(Ap + ks * 32);
            float4 x1 = *(const float4*)(Ap + ks * 32 + 4);
            bf16x8 t;
            t[0] = (short)f2bf(x0.x); t[1] = (short)f2bf(x0.y);
            t[2] = (short)f2bf(x0.z); t[3] = (short)f2bf(x0.w);
            t[4] = (short)f2bf(x1.x); t[5] = (short)f2bf(x1.y);
            t[6] = (short)f2bf(x1.z); t[7] = (short)f2bf(x1.w);
            af[ks] = t;
        }
    } else {
        const unsigned short* Ap = (const unsigned short*)A_ + (size_t)arow * 128 + quad * 8;
#pragma unroll
        for (int ks = 0; ks < 4; ks++) af[ks] = *(const bf16x8*)(Ap + ks * 32);
    }

    constexpr int NFT = F / 16;
#pragma unroll
    for (int ft = 0; ft < NFT; ft++) {
        int f = ft * 16 + r16;
        floatx4 acc = {0.f, 0.f, 0.f, 0.f};
#pragma unroll
        for (int ks = 0; ks < 4; ks++) {
            bf16x8 bfr;
            if (B_F32) {
                const float* Bp = (const float*)Wb_ + (size_t)f * 128 + quad * 8;
                float4 b0 = *(const float4*)(Bp + ks * 32);
                float4 b1 = *(const float4*)(Bp + ks * 32 + 4);
                bfr[0] = (short)f2bf(b0.x); bfr[1] = (short)f2bf(b0.y);
                bfr[2] = (short)f2bf(b0.z); bfr[3] = (short)f2bf(b0.w);
                bfr[4] = (short)f2bf(b1.x); bfr[5] = (short)f2bf(b1.y);
                bfr[6] = (short)f2bf(b1.z); bfr[7] = (short)f2bf(b1.w);
            } else {
                const unsigned short* Bp = (const unsigned short*)Wb_ + (size_t)f * 128 + quad * 8;
                bfr = *(const bf16x8*)(Bp + ks * 32);
            }
            acc = __builtin_amdgcn_mfma_f32_16x16x32_bf16(af[ks], bfr, acc, 0, 0, 0);
        }
        float bv = bias ? bias[f] : 0.f;
#pragma unroll
        for (int rg = 0; rg < 4; rg++) {
            int node = node0 + quad * 4 + rg;
            if (node < M) {
                float o = acc[rg] + bv;
                if (OUT_BF16)
                    ((unsigned short*)Cout)[(size_t)node * F + f] = f2bf(o);
                else
                    ((float*)Cout)[(size_t)node * F + f] = o;
            }
        }
    }
}

// ------ packed: count+rank (782) + GEMM1 unscaled (1563) + W2/WL cvt (24) ----
// GEMM1 no longer needs dis (m kept UNSCALED; dis applied at gather via
// csr-embedded bf16) so it runs in the count kernel's shadow: count blocks are
// atomic-latency-bound, gemm blocks are HBM+MFMA -- complementary mixes.
// W1 is consumed as f32 inline (B_F32); only W2/WL need bf16 conversion.

__global__ __launch_bounds__(256) void k_count_gemm_cvt(const int* __restrict__ dst,
                                                        int* __restrict__ cntp,
                                                        unsigned char* __restrict__ rank,
                                                        const float* __restrict__ x,
                                                        const float* __restrict__ W1,
                                                        unsigned short* __restrict__ A,
                                                        const float* __restrict__ W2,
                                                        const float* __restrict__ WL,
                                                        unsigned short* __restrict__ W2b,
                                                        unsigned short* __restrict__ WLb) {
    if (blockIdx.x < FB) {
        int e8 = (blockIdx.x * 256 + threadIdx.x) * 8;
        int* c = cntp + (blockIdx.x & (NCOPY - 1)) * NN;
        if (e8 < EE) {   // EE % 8 == 0
            int4 d0 = *(const int4*)&dst[e8];
            int4 d1 = *(const int4*)&dst[e8 + 4];
            unsigned r0 = atomicAdd(&c[d0.x], 1);
            unsigned r1 = atomicAdd(&c[d0.y], 1);
            unsigned r2 = atomicAdd(&c[d0.z], 1);
            unsigned r3 = atomicAdd(&c[d0.w], 1);
            unsigned r4 = atomicAdd(&c[d1.x], 1);
            unsigned r5 = atomicAdd(&c[d1.y], 1);
            unsigned r6 = atomicAdd(&c[d1.z], 1);
            unsigned r7 = atomicAdd(&c[d1.w], 1);
            uint2 pk;
            pk.x = (r0 & 255) | ((r1 & 255) << 8) | ((r2 & 255) << 16) | (r3 << 24);
            pk.y = (r4 & 255) | ((r5 & 255) << 8) | ((r6 & 255) << 16) | (r7 << 24);
            *(uint2*)&rank[e8] = pk;
        }
        return;
    }
    if (blockIdx.x < FB + GB) {
        // m1 = x @ W1.T (UNSCALED, bf16) -> A
        gemm_body<128, true, true, true>(blockIdx.x - FB, threadIdx.x, x, W1,
                                         nullptr, A, NN);
        return;
    }
    int i = (blockIdx.x - FB - GB) * 256 + threadIdx.x;   // quad index
    const float* src; unsigned short* dstp; int off;
    if (i < 4096)      { src = W2; dstp = W2b; off = i; }
    else if (i < 6144) { src = WL; dstp = WLb; off = i - 4096; }
    else return;
    float4 f = ((const float4*)src)[off];
    unsigned short q0 = f2bf(f.x), q1 = f2bf(f.y), q2 = f2bf(f.z), q3 = f2bf(f.w);
    ((ushort2*)dstp)[off * 2]     = make_ushort2(q0, q1);
    ((ushort2*)dstp)[off * 2 + 1] = make_ushort2(q2, q3);
}

// scan1: per-node copy-prefix across the 8 cntp copies + 1024-block exclusive
// scan of totals (shfl-based: 2 barriers); block totals -> S.
__global__ __launch_bounds__(1024) void k_scan1(int* __restrict__ cntp,
                                                int* __restrict__ cnt,
                                                int* __restrict__ row_ptr,
                                                int* __restrict__ S) {
    __shared__ int wsh[16];
    int tid = threadIdx.x;
    int i = blockIdx.x * 1024 + tid;
    int s = 0;
    if (i < NN) {
        int a = 0;
#pragma unroll
        for (int p = 0; p < NCOPY; p++) {
            int t = cntp[p * NN + i];
            cntp[p * NN + i] = a;    // within-node prefix across copies
            a += t;
        }
        cnt[i] = a;
        s = a;
    }
    int ln = tid & 63, wv = tid >> 6;
    int sc = s;                       // inclusive wave scan
#pragma unroll
    for (int off = 1; off < 64; off <<= 1) {
        int t = __shfl_up(sc, off);
        if (ln >= off) sc += t;
    }
    if (ln == 63) wsh[wv] = sc;
    __syncthreads();
    if (tid < 16) {                   // exclusive scan of the 16 wave totals
        int w0 = wsh[tid];
        int wc = w0;
#pragma unroll
        for (int off = 1; off < 16; off <<= 1) {
            int t = __shfl_up(wc, off);
            if (tid >= off) wc += t;
        }
        wsh[tid] = wc - w0;
    }
    __syncthreads();
    int total = sc + wsh[wv];                 // inclusive for this thread
    if (i < NN) row_ptr[i] = total - s;       // exclusive
    if (tid == 1023) S[blockIdx.x] = total;   // block total
}

// scan2+scan3 fused: every block redundantly scans the 98 block totals in LDS,
// then finalizes rc/dis and folds absolute row_ptr into the 8 copy cursors.
__global__ __launch_bounds__(256) void k_scan23(const int* __restrict__ row_ptr,
                                                int2* __restrict__ rc,
                                                const int* __restrict__ Sraw, int nb,
                                                const int* __restrict__ cnt,
                                                float* __restrict__ dis,
                                                int* __restrict__ cntp,
                                                unsigned int* __restrict__ Azero,
                                                unsigned int* __restrict__ A2zero) {
    __shared__ int sh[128];
    int tid = threadIdx.x;
    int v = 0;
    if (tid < 128) {
        v = (tid < nb) ? Sraw[tid] : 0;
        sh[tid] = v;
    }
    __syncthreads();
    for (int off = 1; off < 128; off <<= 1) {
        int t = 0;
        if (tid < 128 && tid >= off) t = sh[tid - off];
        __syncthreads();
        if (tid < 128) sh[tid] += t;
        __syncthreads();
    }
    int excl = 0;
    if (tid < 128) excl = sh[tid] - v;
    __syncthreads();
    if (tid < 128) sh[tid] = excl;
    __syncthreads();

    int i = blockIdx.x * 256 + tid;
    if (i < NN) {
        int c = cnt[i];
        int r = row_ptr[i] + sh[i >> 10];
        rc[i] = make_int2(r, c);
        dis[i] = rsqrtf((float)(c + 1));
#pragma unroll
        for (int p = 0; p < NCOPY; p++) cntp[p * NN + i] += r;  // absolute base cursors
    }
    if (blockIdx.x == 0 && tid < 64) { Azero[tid] = 0; A2zero[tid] = 0; }  // zero rows
}

// ---------------- fill (no atomics, dis-embedded entries) --------------------
// slot = cntp[p][d] (absolute cursor, plain gather) + rank[e] (uchar).
// Entry = bf16(dis[src]) in bits 31:17 | src in bits 16:0 -- the gather-side
// scale rides along for free (17 bits cover NN; bf16 of dis>0 has sign=0).

__global__ __launch_bounds__(256) void k_fill(const int* __restrict__ src,
                                              const int* __restrict__ dst,
                                              const unsigned char* __restrict__ rank,
                                              const int* __restrict__ cntp,
                                              const float* __restrict__ dis,
                                              int* __restrict__ csr) {
    int e8 = (blockIdx.x * 256 + threadIdx.x) * 8;
    const int* c = cntp + (blockIdx.x & (NCOPY - 1)) * NN;
    if (e8 < EE) {
        int4 s0 = *(const int4*)&src[e8];
        int4 s1 = *(const int4*)&src[e8 + 4];
        int4 d0 = *(const int4*)&dst[e8];
        int4 d1 = *(const int4*)&dst[e8 + 4];
        uint2 pk = *(const uint2*)&rank[e8];
        csr[c[d0.x] + (pk.x & 255)]         = ((int)f2bf(dis[s0.x]) << 17) | s0.x;
        csr[c[d0.y] + ((pk.x >> 8) & 255)]  = ((int)f2bf(dis[s0.y]) << 17) | s0.y;
        csr[c[d0.z] + ((pk.x >> 16) & 255)] = ((int)f2bf(dis[s0.z]) << 17) | s0.z;
        csr[c[d0.w] + (pk.x >> 24)]         = ((int)f2bf(dis[s0.w]) << 17) | s0.w;
        csr[c[d1.x] + (pk.y & 255)]         = ((int)f2bf(dis[s1.x]) << 17) | s1.x;
        csr[c[d1.y] + ((pk.y >> 8) & 255)]  = ((int)f2bf(dis[s1.y]) << 17) | s1.y;
        csr[c[d1.z] + ((pk.y >> 16) & 255)] = ((int)f2bf(dis[s1.z]) << 17) | s1.z;
        csr[c[d1.w] + (pk.y >> 24)]         = ((int)f2bf(dis[s1.w]) << 17) | s1.w;
    }
}

// ---------------- fused aggregation + GEMM (R2-proven shape) -----------------
// Block = 256 thr = 4 waves = 2 independent 16-node tiles (2 waves/tile).
// Phase A: lane-group g owns node vb+g; 16 lanes gather 8-deep (128B in
// flight/lane). Entries carry bf16(dis[src]) -> accumulate via fma (same
// VALU count as add). m arrays are UNSCALED; self term = dv*m[v].
// Phase B: each wave does half the F-tiles of the 16x128 MFMA GEMM from LDS
// (m2 = h@W2.T UNSCALED, or head out = h@WL.T+bl).

#define FMA8(r, wt)                                                   \
    do {                                                              \
        acc[0] = fmaf(bf2f_lo(r.x), wt, acc[0]);                      \
        acc[1] = fmaf(bf2f_hi(r.x), wt, acc[1]);                      \
        acc[2] = fmaf(bf2f_lo(r.y), wt, acc[2]);                      \
        acc[3] = fmaf(bf2f_hi(r.y), wt, acc[3]);                      \
        acc[4] = fmaf(bf2f_lo(r.z), wt, acc[4]);                      \
        acc[5] = fmaf(bf2f_hi(r.z), wt, acc[5]);                      \
        acc[6] = fmaf(bf2f_lo(r.w), wt, acc[6]);                      \
        acc[7] = fmaf(bf2f_hi(r.w), wt, acc[7]);                      \
    } while (0)

template <bool RES_F32, int F, bool OUT_BF16, bool WRITE_H>
__global__ __launch_bounds__(256) void k_aggemm(const unsigned short* __restrict__ m,
                                                const int2* __restrict__ rc,
                                                const int* __restrict__ csr,
                                                const float* __restrict__ dis,
                                                const float* __restrict__ bias,
                                                const void* __restrict__ res_,
                                                unsigned short* __restrict__ hout,
                                                const unsigned short* __restrict__ Wb,
                                                const float* __restrict__ gbias,
                                                void* __restrict__ gout) {
    __shared__ unsigned short hsh[2][16][136];   // +8 pad: 2-way max on frag reads
    int tid = threadIdx.x;
    int w = tid >> 6, lane = tid & 63;
    int t = w >> 1, hf = w & 1;                  // tile, half
    int tile_base = blockIdx.x * 32 + t * 16;    // NN % 32 == 0: no guards
    int g = lane >> 4;                           // lane-group = node-in-batch
    int r16 = lane & 15;
    int fl = r16 * 8;                            // 8 features per lane
    const char* mb2 = (const char*)m + fl * 2;   // 32-bit row offsets: s<<8

    float4 q0 = *(const float4*)&bias[fl];
    float4 q1 = *(const float4*)&bias[fl + 4];
    float bb[8] = {q0.x, q0.y, q0.z, q0.w, q1.x, q1.y, q1.z, q1.w};

#pragma unroll
    for (int b = 0; b < 2; ++b) {
        int v = tile_base + hf * 8 + b * 4 + g;  // my group's node
        int2 rcv = rc[v];
        int start = rcv.x, c = rcv.y;
        int ab = start & ~3;                     // 16B-aligned csr base
        int sh0 = start - ab;                    // 0..3
        int cm = sh0 + c;                        // iterations cover [0, cm)
        cm = max(cm, __shfl_xor(cm, 16));
        cm = max(cm, __shfl_xor(cm, 32));        // wave-uniform bound

        float acc[8];
#pragma unroll
        for (int j = 0; j < 8; j++) acc[j] = 0.f;

        int4 ia = *(const int4*)&csr[ab];
        int4 ib = *(const int4*)&csr[ab + 4];
        for (int base = 0; base < cm; base += 8) {
            unsigned cc = (unsigned)c;
            int e0 = ((unsigned)(base + 0 - sh0) < cc) ? ia.x : NN;   // NN: zero row, scale 0
            int e1 = ((unsigned)(base + 1 - sh0) < cc) ? ia.y : NN;
            int e2 = ((unsigned)(base + 2 - sh0) < cc) ? ia.z : NN;
            int e3 = ((unsigned)(base + 3 - sh0) < cc) ? ia.w : NN;
            int e4 = ((unsigned)(base + 4 - sh0) < cc) ? ib.x : NN;
            int e5 = ((unsigned)(base + 5 - sh0) < cc) ? ib.y : NN;
            int e6 = ((unsigned)(base + 6 - sh0) < cc) ? ib.z : NN;
            int e7 = ((unsigned)(base + 7 - sh0) < cc) ? ib.w : NN;
            uint4 r0 = *(const uint4*)(mb2 + ((e0 & IMASK) << 8));
            uint4 r1 = *(const uint4*)(mb2 + ((e1 & IMASK) << 8));
            uint4 r2 = *(const uint4*)(mb2 + ((e2 & IMASK) << 8));
            uint4 r3 = *(const uint4*)(mb2 + ((e3 & IMASK) << 8));
            uint4 r4 = *(const uint4*)(mb2 + ((e4 & IMASK) << 8));
            uint4 r5 = *(const uint4*)(mb2 + ((e5 & IMASK) << 8));
            uint4 r6 = *(const uint4*)(mb2 + ((e6 & IMASK) << 8));
            uint4 r7 = *(const uint4*)(mb2 + ((e7 & IMASK) << 8));
            ia = *(const int4*)&csr[ab + base + 8];    // prefetch next (stays in flight)
            ib = *(const int4*)&csr[ab + base + 12];
            float w0 = __uint_as_float(((unsigned)e0 >> 17) << 16);
            float w1 = __uint_as_float(((unsigned)e1 >> 17) << 16);
            float w2 = __uint_as_float(((unsigned)e2 >> 17) << 16);
            float w3 = __uint_as_float(((unsigned)e3 >> 17) << 16);
            float w4 = __uint_as_float(((unsigned)e4 >> 17) << 16);
            float w5 = __uint_as_float(((unsigned)e5 >> 17) << 16);
            float w6 = __uint_as_float(((unsigned)e6 >> 17) << 16);
            float w7 = __uint_as_float(((unsigned)e7 >> 17) << 16);
            FMA8(r0, w0); FMA8(r1, w1); FMA8(r2, w2); FMA8(r3, w3);
            FMA8(r4, w4); FMA8(r5, w5); FMA8(r6, w6); FMA8(r7, w7);
        }

        // batched tail: 64 lanes = 4 nodes x 16 feature-octets
        float dv = dis[v];
        uint4 mv = *(const uint4*)(m + (size_t)v * 128 + fl);
        float mvf[8] = {bf2f_lo(mv.x), bf2f_hi(mv.x), bf2f_lo(mv.y), bf2f_hi(mv.y),
                        bf2f_lo(mv.z), bf2f_hi(mv.z), bf2f_lo(mv.w), bf2f_hi(mv.w)};
        float rr[8];
        if (RES_F32) {
            const float* rp = (const float*)res_ + (size_t)v * 128 + fl;
            float4 a0 = *(const float4*)rp;
            float4 a1 = *(const float4*)(rp + 4);
            rr[0] = a0.x; rr[1] = a0.y; rr[2] = a0.z; rr[3] = a0.w;
            rr[4] = a1.x; rr[5] = a1.y; rr[6] = a1.z; rr[7] = a1.w;
        } else {
            uint4 rv = *(const uint4*)((const unsigned short*)res_ + (size_t)v * 128 + fl);
            rr[0] = bf2f_lo(rv.x); rr[1] = bf2f_hi(rv.x);
            rr[2] = bf2f_lo(rv.y); rr[3] = bf2f_hi(rv.y);
            rr[4] = bf2f_lo(rv.z); rr[5] = bf2f_hi(rv.z);
            rr[6] = bf2f_lo(rv.w); rr[7] = bf2f_hi(rv.w);
        }
        unsigned short po[8];
#pragma unroll
        for (int j = 0; j < 8; j++) {
            float sum = fmaf(mvf[j], dv, acc[j]);    // self term: dv*m[v]
            float tv = fmaxf(fmaf(sum, dv, bb[j]), 0.f) + rr[j];
            po[j] = f2bf(tv);
        }
        uint4 o;
        o.x = (unsigned)po[0] | ((unsigned)po[1] << 16);
        o.y = (unsigned)po[2] | ((unsigned)po[3] << 16);
        o.z = (unsigned)po[4] | ((unsigned)po[5] << 16);
        o.w = (unsigned)po[6] | ((unsigned)po[7] << 16);
        *(uint4*)&hsh[t][hf * 8 + b * 4 + g][fl] = o;
        if (WRITE_H) *(uint4*)&hout[(size_t)v * 128 + fl] = o;
    }

    __syncthreads();   // partner wave's 8 rows must land

    // Phase B: C[tile_base..+15][hf's half of F) = hsh[t] @ Wb.T (UNSCALED +bias)
    int quad = g;
    bf16x8 af[4];
    const unsigned short* Ap = &hsh[t][r16][quad * 8];
#pragma unroll
    for (int ks = 0; ks < 4; ks++) af[ks] = *(const bf16x8*)(Ap + ks * 32);
    constexpr int NFT = F / 16, HFT = NFT / 2;
#pragma unroll
    for (int ftl = 0; ftl < HFT; ftl++) {
        int ft = hf * HFT + ftl;
        int f = ft * 16 + r16;
        const unsigned short* Bp = Wb + (size_t)f * 128 + quad * 8;
        floatx4 a4 = {0.f, 0.f, 0.f, 0.f};
#pragma unroll
        for (int ks = 0; ks < 4; ks++) {
            bf16x8 bfr = *(const bf16x8*)(Bp + ks * 32);
            a4 = __builtin_amdgcn_mfma_f32_16x16x32_bf16(af[ks], bfr, a4, 0, 0, 0);
        }
        float bv = gbias ? gbias[f] : 0.f;
#pragma unroll
        for (int rg = 0; rg < 4; rg++) {
            int node = tile_base + quad * 4 + rg;
            float o = a4[rg] + bv;
            if (OUT_BF16)
                ((unsigned short*)gout)[(size_t)node * F + f] = f2bf(o);
            else
                ((float*)gout)[(size_t)node * F + f] = o;
        }
    }
}

// ---------------- host ----------------

extern "C" void kernel_launch(void* const* d_in, const int* in_sizes, int n_in,
                              void* d_out, int out_size, void* d_ws, size_t ws_size,
                              hipStream_t stream) {
    const float* x   = (const float*)d_in[0];
    const int*   ei  = (const int*)d_in[1];   // [2,E] int32
    const float* W1  = (const float*)d_in[2];
    const float* b1  = (const float*)d_in[3];
    const float* W2  = (const float*)d_in[4];
    const float* b2  = (const float*)d_in[5];
    const float* WL  = (const float*)d_in[6];
    const float* bl  = (const float*)d_in[7];
    float* out = (float*)d_out;

    const int* esrc = ei;
    const int* edst = ei + EE;

    char* w = (char*)d_ws;
    auto alloc = [&](size_t bytes) -> char* {
        char* p = w;
        w += (bytes + 255) & ~(size_t)255;
        return p;
    };
    int*   cntp    = (int*)alloc((size_t)NCOPY * NN * 4);  // 3.2MB XCD-local cursors
    int*   cnt     = (int*)alloc((size_t)NN * 4);
    int*   row_ptr = (int*)alloc((size_t)NN * 4);
    int2*  rc      = (int2*)alloc((size_t)NN * 8);
    float* dis     = (float*)alloc((size_t)NN * 4);
    int*   S       = (int*)alloc(1024 * 4);
    unsigned char* rank = (unsigned char*)alloc((size_t)EE);
    int*   csr     = (int*)alloc((size_t)EE * 4 + 256);    // +slack for aligned prefetch
    unsigned short* W2b = (unsigned short*)alloc(128 * 128 * 2);
    unsigned short* WLb = (unsigned short*)alloc(64 * 128 * 2);
    unsigned short* A   = (unsigned short*)alloc((size_t)(NN + 1) * 128 * 2);  // m1 + zero row
    unsigned short* A2  = (unsigned short*)alloc((size_t)(NN + 1) * 128 * 2);  // m2 + zero row
    unsigned short* B   = (unsigned short*)alloc((size_t)NN * 128 * 2);        // h1

    const int nb_s1 = (NN + 1023) / 1024;     // 98
    const int nb_s23 = (NN + 255) / 256;      // 391

    // zero the histogram via DMA, then packed count+rank | gemm1(m1) | W2/WL cvt
    hipMemsetAsync(cntp, 0, (size_t)NCOPY * NN * 4, stream);
    k_count_gemm_cvt<<<FB + GB + 24, 256, 0, stream>>>(edst, cntp, rank,
                                                       x, W1, A, W2, WL, W2b, WLb);
    // copy-prefix + shfl block scan; then fused S-scan + finalize (+zero rows)
    k_scan1<<<nb_s1, 1024, 0, stream>>>(cntp, cnt, row_ptr, S);
    k_scan23<<<nb_s23, 256, 0, stream>>>(row_ptr, rc, S, nb_s1, cnt, dis, cntp,
                                         (unsigned int*)(A + (size_t)NN * 128),
                                         (unsigned int*)(A2 + (size_t)NN * 128));
    // CSR place (no atomics, dis-embedded entries)
    k_fill<<<FB, 256, 0, stream>>>(esrc, edst, rank, cntp, dis, csr);

    const int nb_agg = NN / 32;   // 3125, exact (NN % 32 == 0)

    // layer 1: h1 = relu(dis*(sum+dv*self)+b1)+x -> B(global)+LDS; m2 = h1@W2.T -> A2
    k_aggemm<true, 128, true, true><<<nb_agg, 256, 0, stream>>>(
        A, rc, csr, dis, b1, x, B, W2b, nullptr, A2);
    // layer 2 + head: h2 (LDS only); out = h2@WL.T+bl
    k_aggemm<false, 64, false, false><<<nb_agg, 256, 0, stream>>>(
        A2, rc, csr, dis, b2, B, nullptr, WLb, bl, out);
}